// Round 7
// baseline (171.084 us; speedup 1.0000x reference)
//
#include <hip/hip_runtime.h>
#include <hip/hip_bf16.h>

// TypedLinear: y[i] = W[types[i]] @ x[i] + b[types[i]]
// B=131072, T=8, IN=OUT=128, fp32 in/out.
// v4: async-DMA pipeline. v2 (52us) and v3 (78us) were both latency-bound
// (1.3-2.0 TB/s, nothing saturated): reg-staged loads got serialized by the
// compiler (v3 VGPR=24 proved it). v4 streams x via global_load_lds (zero
// VGPR, fire-and-forget) into a double-buffered fp32 LDS tile, overlapped
// with compute of the previous tile. Source-side XOR swizzle (m173 pattern)
// gives 2-way-banked LDS reads. Bucketed per-type MFMA compute unchanged
// (verified absmax 0.03125 across v1-v3).

typedef __attribute__((ext_vector_type(8))) short bf16x8;   // 8 bf16 (4 VGPRs)
typedef __attribute__((ext_vector_type(4))) float f32x4;    // MFMA accumulator
typedef __attribute__((ext_vector_type(4))) float float4v;

static constexpr int kT       = 8;     // number of types
static constexpr int kD       = 128;   // IN = OUT = 128
static constexpr int kTileTok = 64;    // tokens per pipeline tile
static constexpr int kTiles   = 4;     // pipeline tiles per block
static constexpr int kBlkTok  = kTileTok * kTiles;  // 256 tokens/block
static constexpr int kThreads = 256;   // 4 waves

__device__ __forceinline__ short f2bf(float f) {
  union { __hip_bfloat16 h; short u; } cv;
  cv.h = __float2bfloat16(f);
  return cv.u;
}

// Prep: convert W (8*128*128 fp32) -> bf16 in workspace (256 KiB, L2-resident).
__global__ __launch_bounds__(256) void wconv_kernel(const float* __restrict__ W,
                                                    short* __restrict__ Wb) {
  const int i = (blockIdx.x * 256 + threadIdx.x) * 8;
  float4v a = *(const float4v*)(W + i);
  float4v b = *(const float4v*)(W + i + 4);
  bf16x8 r;
  r[0] = f2bf(a[0]); r[1] = f2bf(a[1]); r[2] = f2bf(a[2]); r[3] = f2bf(a[3]);
  r[4] = f2bf(b[0]); r[5] = f2bf(b[1]); r[6] = f2bf(b[2]); r[7] = f2bf(b[3]);
  *(bf16x8*)(Wb + i) = r;
}

// 256 threads = 4 waves; block owns 256 tokens = 4 tiles of 64.
// Pipeline: prologue {zero cnts, bucket all 4 tiles, DMA(tile0)};
// per iter i: barrier (drains DMA(i)) -> DMA(i+1) -> compute(i).
// x tile lives fp32 in LDS, XOR-swizzled on 16B granules: LDS slot p of row r
// holds source granule p^(r&7); readers fetch granule g at slot g^(r&7).
__global__ __launch_bounds__(kThreads, 2) void typed_linear_kernel(
    const float* __restrict__ x, const int* __restrict__ types,
    const short* __restrict__ Wb, const float* __restrict__ bias,
    float* __restrict__ y) {
  __shared__ float xb[2][kTileTok * kD];               // 2 x 32 KiB fp32
  __shared__ int s_cnt[kTiles][kT];
  __shared__ unsigned char s_list[kTiles][kT][kTileTok];

  const int tid   = threadIdx.x;
  const long tok0 = (long)blockIdx.x * kBlkTok;

  // --- prologue: zero counters, bucket all 4 tiles (1 token/thread)
  if (tid < kTiles * kT) ((int*)s_cnt)[tid] = 0;
  __syncthreads();
  {
    const int t    = types[tok0 + tid];
    const int tile = tid >> 6;
    const int pos  = atomicAdd(&s_cnt[tile][t], 1);
    s_list[tile][t][pos] = (unsigned char)(tid & 63);
  }

  const int w    = tid >> 6;    // wave 0..3 -> output cols [w*32, w*32+32)
  const int lane = tid & 63;
  const int lr   = lane & 15;   // A-row / B-col / C-col key
  const int lg   = lane >> 4;   // k-group 0..3

  // async DMA of one 64x128 fp32 tile into buf (32 wave-instrs, 8 per wave).
  // Each wave-instr writes 1 KiB = rows {2*rp, 2*rp+1} linearly; the global
  // source is pre-swizzled so linear slot p receives granule p^(r&7).
  auto dma_tile = [&](int buf, int tile) {
    const float* xt = x + (tok0 + (long)tile * kTileTok) * kD;
#pragma unroll
    for (int j = 0; j < 8; ++j) {
      const int rp = w * 8 + j;                 // row-pair 0..31
      const int r  = rp * 2 + (lane >> 5);
      const int p  = lane & 31;                 // 16B granule within row
      const float* src = xt + r * kD + ((p ^ (r & 7)) << 2);
      float* dst = &xb[buf][rp * 2 * kD];       // wave-uniform; HW adds lane*16B
      __builtin_amdgcn_global_load_lds(
          (const __attribute__((address_space(1))) void*)src,
          (__attribute__((address_space(3))) void*)dst, 16, 0, 0);
    }
  };

  dma_tile(0, 0);

  for (int i = 0; i < kTiles; ++i) {
    __syncthreads();                 // drains DMA(i) + prior stores; lists ready
    if (i + 1 < kTiles) dma_tile((i + 1) & 1, i + 1);

    const float* xt   = xb[i & 1];
    const long ytile0 = tok0 + (long)i * kTileTok;

    for (int t = 0; t < kT; ++t) {
      const int cnt = s_cnt[i][t];
      if (cnt == 0) continue;

      // B fragments: B[k][o] = W[t][o][k]; same k-map as A (shared bijection).
      bf16x8 bfr[2][4];
      const short* wrow = Wb + ((t * kD + w * 32 + lr) * kD);
#pragma unroll
      for (int c = 0; c < 2; ++c)
#pragma unroll
        for (int s = 0; s < 4; ++s)
          bfr[c][s] = *(const bf16x8*)(wrow + c * 16 * kD + s * 32 + lg * 8);

      const float bias0 = bias[t * kD + w * 32 + lr];
      const float bias1 = bias[t * kD + w * 32 + 16 + lr];

      for (int m0 = 0; m0 < cnt; m0 += 16) {
        int ia = m0 + lr;
        ia = ia < cnt ? ia : cnt - 1;            // clamped dup for ragged tail
        const int row = s_list[i][t][ia];
        const int m7  = row & 7;

        // A fragments: granule g=(s*8+lg*2) at swizzled slots, cvt fp32->bf16
        bf16x8 afr[4];
#pragma unroll
        for (int s = 0; s < 4; ++s) {
          const int g = s * 8 + lg * 2;
          const float4v lo = *(const float4v*)(xt + row * kD + ((g ^ m7) << 2));
          const float4v hi = *(const float4v*)(xt + row * kD + (((g + 1) ^ m7) << 2));
          bf16x8 a;
          a[0] = f2bf(lo[0]); a[1] = f2bf(lo[1]); a[2] = f2bf(lo[2]); a[3] = f2bf(lo[3]);
          a[4] = f2bf(hi[0]); a[5] = f2bf(hi[1]); a[6] = f2bf(hi[2]); a[7] = f2bf(hi[3]);
          afr[s] = a;
        }

        f32x4 acc0 = {0.f, 0.f, 0.f, 0.f};
        f32x4 acc1 = {0.f, 0.f, 0.f, 0.f};
#pragma unroll
        for (int s = 0; s < 4; ++s) {
          acc0 = __builtin_amdgcn_mfma_f32_16x16x32_bf16(afr[s], bfr[0][s], acc0, 0, 0, 0);
          acc1 = __builtin_amdgcn_mfma_f32_16x16x32_bf16(afr[s], bfr[1][s], acc1, 0, 0, 0);
        }

        // C/D layout (HW-verified): col = lane&15, row = (lane>>4)*4 + reg
#pragma unroll
        for (int r = 0; r < 4; ++r) {
          const int rl = lg * 4 + r;
          if (m0 + rl < cnt) {
            float* yp = y + (ytile0 + s_list[i][t][m0 + rl]) * kD + w * 32 + lr;
            yp[0]  = acc0[r] + bias0;
            yp[16] = acc1[r] + bias1;
          }
        }
      }
    }
  }
}

extern "C" void kernel_launch(void* const* d_in, const int* in_sizes, int n_in,
                              void* d_out, int out_size, void* d_ws, size_t ws_size,
                              hipStream_t stream) {
  const float* x     = (const float*)d_in[0];
  const int*   types = (const int*)d_in[1];
  const float* W     = (const float*)d_in[2];
  const float* bias  = (const float*)d_in[3];
  float*       y     = (float*)d_out;
  short*       Wb    = (short*)d_ws;   // 8*128*128 bf16 = 256 KiB scratch

  const int n_tok = in_sizes[0] / kD;  // 131072

  wconv_kernel<<<(kT * kD * kD) / (256 * 8), 256, 0, stream>>>(W, Wb);
  typed_linear_kernel<<<n_tok / kBlkTok, kThreads, 0, stream>>>(x, types, Wb, bias, y);
}

// Round 8
// 141.351 us; speedup vs baseline: 1.2103x; 1.2103x over previous
//
#include <hip/hip_runtime.h>
#include <hip/hip_bf16.h>

// TypedLinear: y[i] = W[types[i]] @ x[i] + b[types[i]]
// B=131072, T=8, IN=OUT=128, fp32 in/out.
// v5 = v2 (best: 52us) + forced staging MLP. Evidence across v1-v4: perf tracks
// per-wave MLP of the x stream (v2 VGPR=52 meant 12/16 staging loads were sunk
// by the scheduler; v3's VGPR=24 and v4's vmcnt-entangled DMA both regressed).
// Fix: issue all 16 float4 loads, then sched_barrier(0) so they cannot sink;
// 64 VGPRs of staged x live across the clump (launch_bounds cap 128).
// Also: store-row indices via __shfl instead of 4 serial ds_read_u8 per m-tile.
// Compute structure verified since v1 (absmax 0.03125).

typedef __attribute__((ext_vector_type(8))) short bf16x8;   // 8 bf16 (one ds_read_b128)
typedef __attribute__((ext_vector_type(4))) short short4v;  // 4 bf16 (one ds_write_b64)
typedef __attribute__((ext_vector_type(4))) float f32x4;    // MFMA accumulator
typedef __attribute__((ext_vector_type(4))) float float4v;

static constexpr int kBT = 128;   // tokens per block
static constexpr int kT  = 8;     // number of types
static constexpr int kD  = 128;   // IN = OUT = 128

__device__ __forceinline__ short f2bf(float f) {
  union { __hip_bfloat16 h; short u; } cv;
  cv.h = __float2bfloat16(f);
  return cv.u;
}

// Prep: convert W (8*128*128 fp32) -> bf16 in workspace (256 KiB, L2-resident).
__global__ __launch_bounds__(256) void wconv_kernel(const float* __restrict__ W,
                                                    short* __restrict__ Wb) {
  const int i = (blockIdx.x * 256 + threadIdx.x) * 8;
  float4v a = *(const float4v*)(W + i);
  float4v b = *(const float4v*)(W + i + 4);
  bf16x8 r;
  r[0] = f2bf(a[0]); r[1] = f2bf(a[1]); r[2] = f2bf(a[2]); r[3] = f2bf(a[3]);
  r[4] = f2bf(b[0]); r[5] = f2bf(b[1]); r[6] = f2bf(b[2]); r[7] = f2bf(b[3]);
  *(bf16x8*)(Wb + i) = r;
}

// 256 threads = 4 waves; block = 128 consecutive tokens.
// zero cnts -> issue 16 coalesced float4 loads (pinned clump, 16-deep MLP) ->
// barrier -> bucket by type + cvt+swizzled LDS write -> barrier ->
// per type: {W frags from L2, A frags from LDS, 8x mfma_16x16x32_bf16,
// shfl'd store rows, masked scattered stores}.
__global__ __launch_bounds__(256, 4) void typed_linear_kernel(
    const float* __restrict__ x, const int* __restrict__ types,
    const short* __restrict__ Wb, const float* __restrict__ bias,
    float* __restrict__ y) {
  __shared__ short xb[kBT * kD];            // 32 KiB swizzled bf16 x-tile
  __shared__ int s_cnt[kT];
  __shared__ unsigned char s_list[kT][kBT];

  const int tid  = threadIdx.x;
  const int tok0 = blockIdx.x * kBT;

  if (tid < kT) s_cnt[tid] = 0;

  // --- staging: issue ALL 16 coalesced float4 loads back-to-back; the
  // sched_barrier forbids sinking any of them -> true 16-deep MLP per thread.
  const float* xg = x + (size_t)tok0 * kD;
  float4v xr[16];
#pragma unroll
  for (int i = 0; i < 16; ++i)
    xr[i] = *(const float4v*)(xg + i * 1024 + tid * 4);
  __builtin_amdgcn_sched_barrier(0);

  __syncthreads();   // s_cnt zeroes visible (also drains the staged clump)

  // --- bucket by type
  if (tid < kBT) {
    const int t = types[tok0 + tid];
    const int pos = atomicAdd(&s_cnt[t], 1);
    s_list[t][pos] = (unsigned char)tid;
  }

  // --- cvt + swizzled LDS write (16B slot ^= row&7; write is 8B half-slot)
#pragma unroll
  for (int i = 0; i < 16; ++i) {
    const int f    = i * 1024 + tid * 4;    // flat float index in 128x128 slice
    const int row  = f >> 7;
    const int col  = f & 127;               // col%8 in {0,4}
    const int slot = (col >> 3) ^ (row & 7);
    short4v v;
    v[0] = f2bf(xr[i][0]); v[1] = f2bf(xr[i][1]);
    v[2] = f2bf(xr[i][2]); v[3] = f2bf(xr[i][3]);
    *(short4v*)(xb + row * kD + slot * 8 + (col & 7)) = v;
  }
  __syncthreads();

  const int w    = tid >> 6;    // wave 0..3 -> output cols [w*32, w*32+32)
  const int lane = tid & 63;
  const int lr   = lane & 15;   // A-row / B-col / C-col key
  const int lg   = lane >> 4;   // k-group 0..3

  for (int t = 0; t < kT; ++t) {
    const int cnt = s_cnt[t];
    if (cnt == 0) continue;

    // B fragments: B[k][o] = W[t][o][k]; same assumed k-map as A (any shared
    // k-bijection is correct). 8 independent L2 loads, issued up-front.
    bf16x8 bfr[2][4];
    const short* wrow = Wb + ((t * kD + w * 32 + lr) * kD);
#pragma unroll
    for (int c = 0; c < 2; ++c)
#pragma unroll
      for (int s = 0; s < 4; ++s)
        bfr[c][s] = *(const bf16x8*)(wrow + c * 16 * kD + s * 32 + lg * 8);

    const float bias0 = bias[t * kD + w * 32 + lr];
    const float bias1 = bias[t * kD + w * 32 + 16 + lr];

    for (int m0 = 0; m0 < cnt; m0 += 16) {
      int ia = m0 + lr;
      ia = ia < cnt ? ia : cnt - 1;         // clamped dup for ragged tail
      const int rowA = s_list[t][ia];

      // A fragments from swizzled LDS: slot = (s*4+lg) ^ (rowA&7)
      bf16x8 afr[4];
#pragma unroll
      for (int s = 0; s < 4; ++s) {
        const int slot = ((s << 2) + lg) ^ (rowA & 7);
        afr[s] = *(const bf16x8*)(xb + rowA * kD + slot * 8);
      }

      f32x4 acc0 = {0.f, 0.f, 0.f, 0.f};
      f32x4 acc1 = {0.f, 0.f, 0.f, 0.f};
#pragma unroll
      for (int s = 0; s < 4; ++s) {
        acc0 = __builtin_amdgcn_mfma_f32_16x16x32_bf16(afr[s], bfr[0][s], acc0, 0, 0, 0);
        acc1 = __builtin_amdgcn_mfma_f32_16x16x32_bf16(afr[s], bfr[1][s], acc1, 0, 0, 0);
      }

      // C/D layout (HW-verified): col = lane&15, row = (lane>>4)*4 + reg.
      // Store row indices = other lanes' rowA -> shfl, no extra LDS reads.
#pragma unroll
      for (int r = 0; r < 4; ++r) {
        const int rl   = lg * 4 + r;
        const int rowS = __shfl(rowA, rl, 16);   // s_list[t][m0+rl] when valid
        if (m0 + rl < cnt) {
          float* yp = y + (size_t)(tok0 + rowS) * kD + w * 32 + lr;
          yp[0]  = acc0[r] + bias0;
          yp[16] = acc1[r] + bias1;
        }
      }
    }
  }
}

extern "C" void kernel_launch(void* const* d_in, const int* in_sizes, int n_in,
                              void* d_out, int out_size, void* d_ws, size_t ws_size,
                              hipStream_t stream) {
  const float* x     = (const float*)d_in[0];
  const int*   types = (const int*)d_in[1];
  const float* W     = (const float*)d_in[2];
  const float* bias  = (const float*)d_in[3];
  float*       y     = (float*)d_out;
  short*       Wb    = (short*)d_ws;   // 8*128*128 bf16 = 256 KiB scratch

  const int n_tok = in_sizes[0] / kD;  // 131072

  wconv_kernel<<<(kT * kD * kD) / (256 * 8), 256, 0, stream>>>(W, Wb);
  typed_linear_kernel<<<n_tok / kBT, 256, 0, stream>>>(x, types, Wb, bias, y);
}